// Round 3
// baseline (368.003 us; speedup 1.0000x reference)
//
#include <hip/hip_runtime.h>
#include <hip/hip_bf16.h>

// Problem constants
#define NOUT  4096
#define KDIM  1024   // N_SPARSE
#define MROWS 8192   // BATCH*SEQ

typedef __attribute__((ext_vector_type(8))) short bf16x8;  // 8 bf16 = 4 VGPRs
typedef __attribute__((ext_vector_type(4))) float f32x4;   // MFMA 16x16 accumulator

__device__ __forceinline__ unsigned short f2bf(float f) {
  union { float f; unsigned int u; } c; c.f = f;
  unsigned int lsb = (c.u >> 16) & 1u;
  c.u += 0x7fffu + lsb;
  return (unsigned short)(c.u >> 16);
}

__device__ __forceinline__ void gload_lds16(const void* g, void* l) {
  __builtin_amdgcn_global_load_lds(
      (const __attribute__((address_space(1))) void*)g,
      (__attribute__((address_space(3))) void*)l, 16, 0, 0);
}

#define FENCE() asm volatile("" ::: "memory")
#define BAR() do { FENCE(); __builtin_amdgcn_s_barrier(); FENCE(); } while (0)
#define VMW(n) asm volatile("s_waitcnt vmcnt(" #n ")" ::: "memory")

// ---------------------------------------------------------------------------
// Pass 1 (fused): blocks [0, MROWS) gather+convert x rows; blocks
// [MROWS, MROWS+4096) convert sparse_values. The tiny W-convert overlaps
// under the gather's bandwidth instead of being a separate dispatch.
// ---------------------------------------------------------------------------
__global__ __launch_bounds__(256) void prep(const float* __restrict__ x,
                                            const void* __restrict__ idx_raw,
                                            const float* __restrict__ w,
                                            unsigned short* __restrict__ xg,
                                            unsigned short* __restrict__ wb) {
  __shared__ float row[4096];
  __shared__ int sidx[1024];
  const int b = blockIdx.x;
  const int t = threadIdx.x;

  if (b < MROWS) {
    const long long* p64 = (const long long*)idx_raw;
    const int* p32 = (const int*)idx_raw;
    // int64 vs int32 detection: for int32 data, element0-as-int64 >= 2^32
    // (sorted unique indices, second word >= 1), so `< 4096` discriminates.
    const bool is64 = ((unsigned long long)p64[0]) < 4096ull;
    const float* src = x + (size_t)b * 4096;
#pragma unroll
    for (int i = 0; i < 4; ++i)
      ((float4*)row)[t + 256 * i] = ((const float4*)src)[t + 256 * i];
    if (is64) {
#pragma unroll
      for (int i = 0; i < 4; ++i) sidx[t + 256 * i] = (int)p64[t + 256 * i];
    } else {
#pragma unroll
      for (int i = 0; i < 4; ++i) sidx[t + 256 * i] = p32[t + 256 * i];
    }
    __syncthreads();
    ushort4 o;
    o.x = f2bf(row[sidx[4 * t + 0]]);
    o.y = f2bf(row[sidx[4 * t + 1]]);
    o.z = f2bf(row[sidx[4 * t + 2]]);
    o.w = f2bf(row[sidx[4 * t + 3]]);
    ((ushort4*)(xg + (size_t)b * 1024))[t] = o;
  } else {
    const int i = (b - MROWS) * 256 + t;   // 4096 blocks x 256 x (4 elems)
    float4 v = ((const float4*)w)[i];
    ushort4 o;
    o.x = f2bf(v.x); o.y = f2bf(v.y); o.z = f2bf(v.z); o.w = f2bf(v.w);
    ((ushort4*)wb)[i] = o;
  }
}

// ---------------------------------------------------------------------------
// Pass 2: 256x256 tile, BK=32, 8 waves (2Mx4N), LDS 64 KiB -> 2 blocks/CU.
// One K-tile per phase: STAGE(t+1) -> vmcnt(4) -> bar -> ds_read -> 32 MFMA
// -> bar. Counted vmcnt (never 0 in main loop); T5 setprio; T1 XCD swizzle.
//
// LDS swizzle (BK=32, 64B rows): tile = 256 rows x 4 chunks of 16B, stored as
// slot(row,chunk) = (row>>1)*8 + (((chunk<<1)|(row&1)) ^ ((row>>1)&7)).
// Reader (16 lanes, rows R..R+15, fixed k-octet) then hits each 4-bank group
// with exactly 2 lanes -> 2-way aliasing = free (m136). Writer side (rule
// #21): linear global_load_lds dest (slot = tid) + inverse-mapped global
// source address; map round-trip verified.
// ---------------------------------------------------------------------------
__global__ __launch_bounds__(512, 4) void gemm256(const unsigned short* __restrict__ A,
                                                  const unsigned short* __restrict__ B,
                                                  float* __restrict__ C) {
  __shared__ __align__(16) unsigned short lds[32768];  // 64 KiB: 2 bufs x (A 16K | B 16K)

  const int tid = threadIdx.x;
  const int lane = tid & 63;
  const int wid = tid >> 6;
  const int wm = wid >> 2, wn = wid & 3;      // 2 x 4 wave grid, per-wave 128x64
  const int l15 = lane & 15, lq = lane >> 4;

  // T1 XCD-aware swizzle: grid 512 = 8 XCDs x 64 contiguous tiles
  const int bid = blockIdx.x;
  const int swz = (bid & 7) * 64 + (bid >> 3);
  const int bm0 = (swz >> 4) * 256;   // 32 M-tiles
  const int bn0 = (swz & 15) * 256;   // 16 N-tiles

  // ---- staging map: thread t owns linear LDS slot t (16B) in each half-tile;
  // invert the swizzle to find which (row, chunk) of the global tile it holds.
  const int pr   = tid >> 3;
  const int c8p  = (tid & 7) ^ (pr & 7);
  const int gRow = 2 * pr + (c8p & 1);   // 0..127 (second call: +128)
  const int gChk = c8p >> 1;             // 0..3
  const unsigned short* Ag = A + (size_t)(bm0 + gRow) * KDIM + gChk * 8;
  const unsigned short* Bg = B + (size_t)(bn0 + gRow) * KDIM + gChk * 8;
  const int dstA = tid * 8;  // ushort offset (16B per thread)

  // ---- read map: element (row, k-octet lq) lives at ushort offset
  // (row>>1)*64 + ((((lq<<1)|(row&1)) ^ ((row>>1)&7))*8 within the tile.
  const int c8r = ((lq << 1) | (l15 & 1)) ^ (l15 >> 1);
  const int aBase = wm * 4096 + (l15 >> 1) * 64 + c8r * 8;           // A rows wm*128+mf*16+l15
  const int bBase = 8192 + wn * 2048 + (l15 >> 1) * 64 + c8r * 8;    // B rows wn*64+nf*16+l15

  f32x4 acc[8][4] = {};

#define STAGE(d, t) do {                                             \
    unsigned short* Lb = lds + (d) * 16384;                          \
    gload_lds16(Ag + (t) * 32,               Lb + dstA);             \
    gload_lds16(Ag + 128 * KDIM + (t) * 32,  Lb + 4096 + dstA);      \
    gload_lds16(Bg + (t) * 32,               Lb + 8192 + dstA);      \
    gload_lds16(Bg + 128 * KDIM + (t) * 32,  Lb + 12288 + dstA);     \
  } while (0)

  STAGE(0, 0);

  for (int t = 0; t < 32; ++t) {
    const int d = t & 1;
    if (t < 31) {
      STAGE(d ^ 1, t + 1);   // prefetch next K-tile into other buffer
      VMW(4);                // current tile landed; next tile's 4 in flight
    } else {
      VMW(0);                // tail drain only
    }
    BAR();
    const unsigned short* La = lds + d * 16384;
    bf16x8 bfr[4];
#pragma unroll
    for (int nf = 0; nf < 4; ++nf)
      bfr[nf] = *(const bf16x8*)(La + bBase + nf * 512);
    __builtin_amdgcn_s_setprio(1);
#pragma unroll
    for (int mf = 0; mf < 8; ++mf) {
      bf16x8 af = *(const bf16x8*)(La + aBase + mf * 512);
#pragma unroll
      for (int nf = 0; nf < 4; ++nf)
        acc[mf][nf] = __builtin_amdgcn_mfma_f32_16x16x32_bf16(af, bfr[nf], acc[mf][nf], 0, 0, 0);
    }
    __builtin_amdgcn_s_setprio(0);
    BAR();   // protect this buffer from next iteration's prefetch overwrite
  }
#undef STAGE

  // Epilogue. C/D layout (m89): col = lane&15, row = (lane>>4)*4 + reg.
  float* Crow = C + (size_t)(bm0 + wm * 128 + lq * 4) * NOUT + bn0 + wn * 64 + l15;
#pragma unroll
  for (int mf = 0; mf < 8; ++mf)
#pragma unroll
    for (int nf = 0; nf < 4; ++nf)
#pragma unroll
      for (int j = 0; j < 4; ++j)
        Crow[(size_t)(mf * 16 + j) * NOUT + nf * 16] = acc[mf][nf][j];
}

extern "C" void kernel_launch(void* const* d_in, const int* in_sizes, int n_in,
                              void* d_out, int out_size, void* d_ws, size_t ws_size,
                              hipStream_t stream) {
  const float* x   = (const float*)d_in[0];   // [4,2048,4096] f32
  const float* sv  = (const float*)d_in[1];   // [4096,1024] f32
  const void*  idx = d_in[2];                 // [1024] int32 or int64
  float* out = (float*)d_out;                 // [4,2048,4096] f32

  unsigned short* xg = (unsigned short*)d_ws;                 // [8192,1024] bf16
  unsigned short* wb = xg + (size_t)MROWS * KDIM;             // [4096,1024] bf16

  prep<<<MROWS + 4096, 256, 0, stream>>>(x, idx, sv, xg, wb);

  gemm256<<<512, 512, 0, stream>>>(xg, wb, out);  // (16 N x 32 M tiles)
}

// Round 4
// 119.233 us; speedup vs baseline: 3.0864x; 3.0864x over previous
//
#include <hip/hip_runtime.h>
#include <hip/hip_bf16.h>

// Problem constants
#define NOUT  4096
#define KDIM  1024   // N_SPARSE
#define MROWS 8192   // BATCH*SEQ

typedef __attribute__((ext_vector_type(8))) short bf16x8;    // 8 bf16 = 4 VGPRs
typedef __attribute__((ext_vector_type(16))) float f32x16;   // MFMA 32x32 accumulator

__device__ __forceinline__ unsigned short f2bf(float f) {
  union { float f; unsigned int u; } c; c.f = f;
  unsigned int lsb = (c.u >> 16) & 1u;
  c.u += 0x7fffu + lsb;
  return (unsigned short)(c.u >> 16);
}

__device__ __forceinline__ void gload_lds16(const void* g, void* l) {
  __builtin_amdgcn_global_load_lds(
      (const __attribute__((address_space(1))) void*)g,
      (__attribute__((address_space(3))) void*)l, 16, 0, 0);
}

#define FENCE() asm volatile("" ::: "memory")
#define BAR() do { FENCE(); __builtin_amdgcn_s_barrier(); FENCE(); } while (0)
#define VMW(n) asm volatile("s_waitcnt vmcnt(" #n ")" ::: "memory")

// ---------------------------------------------------------------------------
// Pass 1 (fused): blocks [0,2048) gather+convert 4 x-rows each (512 thr,
// 8 float4 in flight per thread for latency hiding); blocks [2048,2560)
// convert sparse_values (4 float4 per thread).
// ---------------------------------------------------------------------------
__global__ __launch_bounds__(512) void prep(const float* __restrict__ x,
                                            const void* __restrict__ idx_raw,
                                            const float* __restrict__ w,
                                            unsigned short* __restrict__ xg,
                                            unsigned short* __restrict__ wb) {
  __shared__ float rows[16384];   // 64 KiB: 4 rows of 4096 f32
  __shared__ int sidx[1024];
  const int b = blockIdx.x;
  const int t = threadIdx.x;

  if (b < 2048) {
    const long long* p64 = (const long long*)idx_raw;
    const int* p32 = (const int*)idx_raw;
    // int64 vs int32 detection: for int32 data, element0-as-int64 >= 2^32
    // (sorted unique indices, second word >= 1), so `< 4096` discriminates.
    const bool is64 = ((unsigned long long)p64[0]) < 4096ull;
    const float* src = x + (size_t)b * 4 * 4096;
#pragma unroll
    for (int i = 0; i < 8; ++i)
      ((float4*)rows)[t + 512 * i] = ((const float4*)src)[t + 512 * i];
    if (is64) {
      sidx[t] = (int)p64[t];
      sidx[t + 512] = (int)p64[t + 512];
    } else {
      sidx[t] = p32[t];
      sidx[t + 512] = p32[t + 512];
    }
    __syncthreads();
    ushort4* dst = (ushort4*)(xg + (size_t)b * 4 * 1024);
#pragma unroll
    for (int i = 0; i < 2; ++i) {
      const int q = t + 512 * i;      // ushort4 index within 4 output rows
      const int e = 4 * q;
      const int rbase = (e >> 10) * 4096;
      const int k = e & 1023;
      ushort4 o;
      o.x = f2bf(rows[rbase + sidx[k + 0]]);
      o.y = f2bf(rows[rbase + sidx[k + 1]]);
      o.z = f2bf(rows[rbase + sidx[k + 2]]);
      o.w = f2bf(rows[rbase + sidx[k + 3]]);
      dst[q] = o;
    }
  } else {
    const int i0 = (b - 2048) * 2048 + t;
#pragma unroll
    for (int j = 0; j < 4; ++j) {
      float4 v = ((const float4*)w)[i0 + 512 * j];
      ushort4 o;
      o.x = f2bf(v.x); o.y = f2bf(v.y); o.z = f2bf(v.z); o.w = f2bf(v.w);
      ((ushort4*)wb)[i0 + 512 * j] = o;
    }
  }
}

// ---------------------------------------------------------------------------
// Pass 2: 256x256 8-phase bf16 GEMM, now on v_mfma_f32_32x32x16_bf16
// (µbench 2495 TF vs 2176 for 16x16; half the instruction count).
// Structure (staging, swizzle, VMW schedule, phases) identical to the
// verified round-2 kernel. C[m,n] = sum_k A[m,k] B[n,k].
//   A: [8192,1024] bf16 row-major, B: [4096,1024] bf16 row-major, C: f32.
// 512 thr = 8 waves (2M x 4N), per-wave 128x64, BK=64, 16 K-tiles,
// 2 K-tiles per iteration, LDS 128 KiB.
// Swizzle: 16B-chunk XOR (row&7) on global source + ds_read address; LDS
// dest linear (rule #21). 32x32 frag read: 32 rows x 2 k-halves spread
// uniformly 8 lanes per 4-bank group -> conflict-free.
// ---------------------------------------------------------------------------
__global__ __launch_bounds__(512, 2) void gemm256(const unsigned short* __restrict__ A,
                                                  const unsigned short* __restrict__ B,
                                                  float* __restrict__ C) {
  __shared__ __align__(16) unsigned short lds[65536];  // 128 KiB

  const int tid = threadIdx.x;
  const int lane = tid & 63;
  const int wid = tid >> 6;
  const int wm = wid >> 2, wn = wid & 3;       // 2 x 4 wave grid
  const int l31 = lane & 31, lh = lane >> 5;   // 32x32 frag: row, k-half
  const int sw = l31 & 7;

  const int bn0 = blockIdx.x * 256;
  const int bm0 = blockIdx.y * 256;

  // ---- staging map (identical to round 2): thread t owns linear LDS 16B
  // slot t per half-tile; global source pre-applies the inverse swizzle.
  const int pr = tid >> 3;
  const int cg = (tid & 7) ^ (pr & 7);
  const unsigned short* Ag = A + (size_t)(bm0 + pr) * KDIM + cg * 8;
  const unsigned short* Bg = B + (size_t)(bn0 + pr) * KDIM + cg * 8;
  const int tid8 = tid * 8;

  // ---- ds_read maps: element (row R, k-octet o) at ushort offset
  // R*64 + ((o ^ (R&7))*8 within a tile. Lane reads row l31 of its frag,
  // octets o = 2*kb + lh for kb=0..3.
  const int cK0 = ((0 + lh) ^ sw) * 8;
  const int cK1 = ((2 + lh) ^ sw) * 8;
  const int cK2 = ((4 + lh) ^ sw) * 8;
  const int cK3 = ((6 + lh) ^ sw) * 8;
  const int aRow = wm * 8192 + l31 * 64;                 // + D*16384 + mh*4096 + mf*2048
  const int bRow = 32768 + wn * 4096 + l31 * 64;         // + D*16384 + nf*2048

  f32x16 acc[4][2] = {};
  bf16x8 a[2][4], bN0[4], bN1[4];

#define LOAD_A(D, MH) do {                                                        \
    const unsigned short* _p = lds + (D) * 16384 + aRow + (MH) * 4096;            \
    a[0][0] = *(const bf16x8*)(_p + cK0);        a[0][1] = *(const bf16x8*)(_p + cK1);         \
    a[0][2] = *(const bf16x8*)(_p + cK2);        a[0][3] = *(const bf16x8*)(_p + cK3);         \
    a[1][0] = *(const bf16x8*)(_p + 2048 + cK0); a[1][1] = *(const bf16x8*)(_p + 2048 + cK1);  \
    a[1][2] = *(const bf16x8*)(_p + 2048 + cK2); a[1][3] = *(const bf16x8*)(_p + 2048 + cK3);  \
  } while (0)

#define LOAD_B(D, NF, R) do {                                                     \
    const unsigned short* _p = lds + (D) * 16384 + bRow + (NF) * 2048;            \
    R[0] = *(const bf16x8*)(_p + cK0); R[1] = *(const bf16x8*)(_p + cK1);         \
    R[2] = *(const bf16x8*)(_p + cK2); R[3] = *(const bf16x8*)(_p + cK3);         \
  } while (0)

#define STAGE_A(D, T, H) do {                                                     \
    gload_lds16(Ag + (size_t)((H) * 128) * KDIM + (T) * 64,                       \
                lds + (D) * 16384 + (H) * 8192 + tid8);                           \
    gload_lds16(Ag + (size_t)((H) * 128 + 64) * KDIM + (T) * 64,                  \
                lds + (D) * 16384 + (H) * 8192 + 4096 + tid8);                    \
  } while (0)

#define STAGE_B(D, T, H) do {                                                     \
    gload_lds16(Bg + (size_t)((H) * 128) * KDIM + (T) * 64,                       \
                lds + 32768 + (D) * 16384 + (H) * 8192 + tid8);                   \
    gload_lds16(Bg + (size_t)((H) * 128 + 64) * KDIM + (T) * 64,                  \
                lds + 32768 + (D) * 16384 + (H) * 8192 + 4096 + tid8);            \
  } while (0)

#define MFMA_Q(MH, NH, R) do {                                                    \
    __builtin_amdgcn_s_setprio(1);                                                \
    _Pragma("unroll") for (int kb = 0; kb < 4; ++kb) {                            \
      _Pragma("unroll") for (int mf = 0; mf < 2; ++mf) {                          \
        acc[(MH)*2+mf][NH] = __builtin_amdgcn_mfma_f32_32x32x16_bf16(             \
            a[mf][kb], R[kb], acc[(MH)*2+mf][NH], 0, 0, 0);                       \
      }                                                                           \
    }                                                                             \
    __builtin_amdgcn_s_setprio(0);                                                \
  } while (0)

  // ---- prologue: tile0 (buf0) fully + tile1 (buf1) B-halves.
  STAGE_B(0, 0, 0); STAGE_B(0, 0, 1);
  STAGE_A(0, 0, 0); STAGE_A(0, 0, 1);
  STAGE_B(1, 1, 0); STAGE_B(1, 1, 1);
  VMW(4);
  BAR();

  // ---- main loop (identical schedule to round 2): iteration i computes
  // K-tiles 2i (buf0, P1-P4) and 2i+1 (buf1, P5-P8); every overwritten
  // half-tile is dead; vmcnt(4) only at P4/P8 (never drained in-loop).
  for (int i = 0; i < 8; ++i) {
    const int tA1 = 2 * i + 1;
    const int tN0 = (2 * i + 2) & 15;
    const int tN1 = (2 * i + 3) & 15;

    // P1: buf0 (M0,N0)
    LOAD_A(0, 0); LOAD_B(0, 0, bN0); STAGE_A(1, tA1, 0);
    BAR(); MFMA_Q(0, 0, bN0); BAR();
    // P2: buf0 (M0,N1)
    LOAD_B(0, 1, bN1); STAGE_A(1, tA1, 1);
    BAR(); MFMA_Q(0, 1, bN1); BAR();
    // P3: buf0 (M1,N0)
    LOAD_A(0, 1); STAGE_B(0, tN0, 0);
    BAR(); MFMA_Q(1, 0, bN0); BAR();
    // P4: buf0 (M1,N1) + gate for buf1
    STAGE_B(0, tN0, 1);
    BAR(); MFMA_Q(1, 1, bN1); VMW(4); BAR();
    // P5: buf1 (M0,N0)
    LOAD_A(1, 0); LOAD_B(1, 0, bN0); STAGE_A(0, tN0, 0);
    BAR(); MFMA_Q(0, 0, bN0); BAR();
    // P6: buf1 (M0,N1)
    LOAD_B(1, 1, bN1); STAGE_A(0, tN0, 1);
    BAR(); MFMA_Q(0, 1, bN1); BAR();
    // P7: buf1 (M1,N0)
    LOAD_A(1, 1); STAGE_B(1, tN1, 0);
    BAR(); MFMA_Q(1, 0, bN0); BAR();
    // P8: buf1 (M1,N1) + gate for next buf0
    STAGE_B(1, tN1, 1);
    BAR(); MFMA_Q(1, 1, bN1); VMW(4); BAR();
  }

  // ---- epilogue. 32x32 C/D (m74/m101): col = lane&31,
  // row = (reg&3) + 8*(reg>>2) + 4*(lane>>5).
  VMW(0);
  float* base = C + (size_t)(bm0 + wm * 128) * NOUT + bn0 + wn * 64;
#pragma unroll
  for (int mf = 0; mf < 4; ++mf)
#pragma unroll
    for (int nf = 0; nf < 2; ++nf) {
      f32x16 v = acc[mf][nf];
#pragma unroll
      for (int r = 0; r < 16; ++r) {
        const int rowi = mf * 32 + (r & 3) + 8 * (r >> 2) + 4 * lh;
        base[(size_t)rowi * NOUT + nf * 32 + l31] = v[r];
      }
    }

#undef LOAD_A
#undef LOAD_B
#undef STAGE_A
#undef STAGE_B
#undef MFMA_Q
}

extern "C" void kernel_launch(void* const* d_in, const int* in_sizes, int n_in,
                              void* d_out, int out_size, void* d_ws, size_t ws_size,
                              hipStream_t stream) {
  const float* x   = (const float*)d_in[0];   // [4,2048,4096] f32
  const float* sv  = (const float*)d_in[1];   // [4096,1024] f32
  const void*  idx = d_in[2];                 // [1024] int32 or int64
  float* out = (float*)d_out;                 // [4,2048,4096] f32

  unsigned short* xg = (unsigned short*)d_ws;                 // [8192,1024] bf16
  unsigned short* wb = xg + (size_t)MROWS * KDIM;             // [4096,1024] bf16

  prep<<<2560, 512, 0, stream>>>(x, idx, sv, xg, wb);

  dim3 grid(NOUT / 256, MROWS / 256);  // (16, 32) = 512 blocks
  gemm256<<<grid, 512, 0, stream>>>(xg, wb, out);
}

// Round 5
// 114.617 us; speedup vs baseline: 3.2107x; 1.0403x over previous
//
#include <hip/hip_runtime.h>
#include <hip/hip_bf16.h>

// Problem constants
#define NOUT  4096
#define KDIM  1024   // N_SPARSE
#define MROWS 8192   // BATCH*SEQ

typedef __attribute__((ext_vector_type(8))) short bf16x8;    // 8 bf16 = 4 VGPRs
typedef __attribute__((ext_vector_type(16))) float f32x16;   // MFMA 32x32 accumulator

__device__ __forceinline__ unsigned short f2bf(float f) {
  union { float f; unsigned int u; } c; c.f = f;
  unsigned int lsb = (c.u >> 16) & 1u;
  c.u += 0x7fffu + lsb;
  return (unsigned short)(c.u >> 16);
}

__device__ __forceinline__ void gload_lds16(const void* g, void* l) {
  __builtin_amdgcn_global_load_lds(
      (const __attribute__((address_space(1))) void*)g,
      (__attribute__((address_space(3))) void*)l, 16, 0, 0);
}

#define FENCE() asm volatile("" ::: "memory")
#define BAR() do { FENCE(); __builtin_amdgcn_s_barrier(); FENCE(); } while (0)
#define VMW(n) asm volatile("s_waitcnt vmcnt(" #n ")" ::: "memory")

// ---------------------------------------------------------------------------
// Pass 1 (fused, no LDS): blocks [0,2048) gather+convert 4 x-rows each via
// scattered global loads (sorted idx -> L1-line reuse); blocks [2048,2560)
// convert sparse_values. Per thread: 1-2 idx vector loads (idx is L2-resident),
// 8 gathers, 2 ushort4 stores.
// ---------------------------------------------------------------------------
__global__ __launch_bounds__(512) void prep(const float* __restrict__ x,
                                            const void* __restrict__ idx_raw,
                                            const float* __restrict__ w,
                                            unsigned short* __restrict__ xg,
                                            unsigned short* __restrict__ wb) {
  const int b = blockIdx.x;
  const int t = threadIdx.x;

  if (b < 2048) {
    const long long* p64 = (const long long*)idx_raw;
    // int64 vs int32 detection: for int32 data, element0-as-int64 >= 2^32
    // (sorted unique indices, second word >= 1), so `< 4096` discriminates.
    const bool is64 = ((unsigned long long)p64[0]) < 4096ull;
    const float* xb = x + (size_t)b * 4 * 4096;
    ushort4* dst = (ushort4*)(xg + (size_t)b * 4 * 1024);
#pragma unroll
    for (int i = 0; i < 2; ++i) {
      const int q = t + 512 * i;      // ushort4 slot within the 4 rows: 0..1023
      const int row = q >> 8;         // 0..3
      const int k = (q & 255) * 4;    // idx position
      int ka0, ka1, ka2, ka3;
      if (is64) {
        longlong2 v0 = ((const longlong2*)p64)[(k >> 1) + 0];
        longlong2 v1 = ((const longlong2*)p64)[(k >> 1) + 1];
        ka0 = (int)v0.x; ka1 = (int)v0.y; ka2 = (int)v1.x; ka3 = (int)v1.y;
      } else {
        int4 v = ((const int4*)idx_raw)[k >> 2];
        ka0 = v.x; ka1 = v.y; ka2 = v.z; ka3 = v.w;
      }
      const float* rp = xb + row * 4096;
      ushort4 o;
      o.x = f2bf(rp[ka0]); o.y = f2bf(rp[ka1]);
      o.z = f2bf(rp[ka2]); o.w = f2bf(rp[ka3]);
      dst[q] = o;
    }
  } else {
    const int i0 = (b - 2048) * 2048 + t;
#pragma unroll
    for (int j = 0; j < 4; ++j) {
      float4 v = ((const float4*)w)[i0 + 512 * j];
      ushort4 o;
      o.x = f2bf(v.x); o.y = f2bf(v.y); o.z = f2bf(v.z); o.w = f2bf(v.w);
      ((ushort4*)wb)[i0 + 512 * j] = o;
    }
  }
}

// ---------------------------------------------------------------------------
// Pass 2: 256x256 8-phase bf16 GEMM on v_mfma_f32_32x32x16_bf16.
// Identical to round 4 EXCEPT the LDS swizzle now uses 4 row bits:
//   granule(row, chunk) = chunk ^ (row&7) ^ ((row>>3)&3)
// so a 32x32 fragment read (rows r..r+31, 2 chunk values) has every 16B
// granule hit by exactly 2 lanes per 16-lane group (distinct rows) -- the
// same distribution as the measured-conflict-free round-2 16x16 map.
// Both sides use the same XOR (rule #21): linear global_load_lds dest +
// inverse-mapped global source + mapped ds_read address.
//   A: [8192,1024] bf16 row-major, B: [4096,1024] bf16 row-major, C: f32.
// 512 thr = 8 waves (2M x 4N), per-wave 128x64, BK=64, 16 K-tiles,
// 2 K-tiles per iteration, LDS 128 KiB, counted vmcnt(4) at P4/P8 only.
// ---------------------------------------------------------------------------
__global__ __launch_bounds__(512, 2) void gemm256(const unsigned short* __restrict__ A,
                                                  const unsigned short* __restrict__ B,
                                                  float* __restrict__ C) {
  __shared__ __align__(16) unsigned short lds[65536];  // 128 KiB

  const int tid = threadIdx.x;
  const int lane = tid & 63;
  const int wid = tid >> 6;
  const int wm = wid >> 2, wn = wid & 3;       // 2 x 4 wave grid
  const int l31 = lane & 31, lh = lane >> 5;   // 32x32 frag: row, k-half

  const int bn0 = blockIdx.x * 256;
  const int bm0 = blockIdx.y * 256;

  // ---- staging map: thread t owns linear LDS 16B slot t per 64-row region;
  // region row r = t>>3, granule g = t&7 holds global k-octet
  // c = g ^ (r&7) ^ ((r>>3)&3).
  const int pr = tid >> 3;
  const int cg = (tid & 7) ^ (pr & 7) ^ ((pr >> 3) & 3);
  const unsigned short* Ag = A + (size_t)(bm0 + pr) * KDIM + cg * 8;
  const unsigned short* Bg = B + (size_t)(bn0 + pr) * KDIM + cg * 8;
  const int tid8 = tid * 8;

  // ---- ds_read map: element (row R, k-octet c) at ushort offset
  // R*64 + ((c ^ (R&7) ^ ((R>>3)&3)) * 8 within a tile. Frag rows are
  // base32 + l31 (base32 multiple of 32) -> XOR term = (l31&7)^(l31>>3).
  const int sw8 = (l31 & 7) ^ (l31 >> 3);
  const int cK0 = (lh ^ sw8) * 8;   // kb=0 (chunk c = 2kb|lh)
  const int cK1 = cK0 ^ 16;         // kb=1
  const int cK2 = cK0 ^ 32;         // kb=2
  const int cK3 = cK0 ^ 48;         // kb=3
  const int aRow = wm * 8192 + l31 * 64;            // + D*16384 + MH*4096 + mf*2048
  const int bRow = 32768 + wn * 4096 + l31 * 64;    // + D*16384 + NF*2048

  f32x16 acc[4][2] = {};
  bf16x8 a[2][4], bN0[4], bN1[4];

#define LOAD_A(D, MH) do {                                                        \
    const unsigned short* _p = lds + (D) * 16384 + aRow + (MH) * 4096;            \
    a[0][0] = *(const bf16x8*)(_p + cK0);        a[0][1] = *(const bf16x8*)(_p + cK1);         \
    a[0][2] = *(const bf16x8*)(_p + cK2);        a[0][3] = *(const bf16x8*)(_p + cK3);         \
    a[1][0] = *(const bf16x8*)(_p + 2048 + cK0); a[1][1] = *(const bf16x8*)(_p + 2048 + cK1);  \
    a[1][2] = *(const bf16x8*)(_p + 2048 + cK2); a[1][3] = *(const bf16x8*)(_p + 2048 + cK3);  \
  } while (0)

#define LOAD_B(D, NF, R) do {                                                     \
    const unsigned short* _p = lds + (D) * 16384 + bRow + (NF) * 2048;            \
    R[0] = *(const bf16x8*)(_p + cK0); R[1] = *(const bf16x8*)(_p + cK1);         \
    R[2] = *(const bf16x8*)(_p + cK2); R[3] = *(const bf16x8*)(_p + cK3);         \
  } while (0)

#define STAGE_A(D, T, H) do {                                                     \
    gload_lds16(Ag + (size_t)((H) * 128) * KDIM + (T) * 64,                       \
                lds + (D) * 16384 + (H) * 8192 + tid8);                           \
    gload_lds16(Ag + (size_t)((H) * 128 + 64) * KDIM + (T) * 64,                  \
                lds + (D) * 16384 + (H) * 8192 + 4096 + tid8);                    \
  } while (0)

#define STAGE_B(D, T, H) do {                                                     \
    gload_lds16(Bg + (size_t)((H) * 128) * KDIM + (T) * 64,                       \
                lds + 32768 + (D) * 16384 + (H) * 8192 + tid8);                   \
    gload_lds16(Bg + (size_t)((H) * 128 + 64) * KDIM + (T) * 64,                  \
                lds + 32768 + (D) * 16384 + (H) * 8192 + 4096 + tid8);            \
  } while (0)

#define MFMA_Q(MH, NH, R) do {                                                    \
    __builtin_amdgcn_s_setprio(1);                                                \
    _Pragma("unroll") for (int kb = 0; kb < 4; ++kb) {                            \
      _Pragma("unroll") for (int mf = 0; mf < 2; ++mf) {                          \
        acc[(MH)*2+mf][NH] = __builtin_amdgcn_mfma_f32_32x32x16_bf16(             \
            a[mf][kb], R[kb], acc[(MH)*2+mf][NH], 0, 0, 0);                       \
      }                                                                           \
    }                                                                             \
    __builtin_amdgcn_s_setprio(0);                                                \
  } while (0)

  // ---- prologue: tile0 (buf0) fully + tile1 (buf1) B-halves.
  STAGE_B(0, 0, 0); STAGE_B(0, 0, 1);
  STAGE_A(0, 0, 0); STAGE_A(0, 0, 1);
  STAGE_B(1, 1, 0); STAGE_B(1, 1, 1);
  VMW(4);
  BAR();

  // ---- main loop: iteration i computes K-tiles 2i (buf0, P1-P4) and 2i+1
  // (buf1, P5-P8); every overwritten half-tile is dead at its stage slot;
  // vmcnt(4) only at P4/P8 (never drained in-loop).
  for (int i = 0; i < 8; ++i) {
    const int tA1 = 2 * i + 1;
    const int tN0 = (2 * i + 2) & 15;
    const int tN1 = (2 * i + 3) & 15;

    // P1: buf0 (M0,N0)
    LOAD_A(0, 0); LOAD_B(0, 0, bN0); STAGE_A(1, tA1, 0);
    BAR(); MFMA_Q(0, 0, bN0); BAR();
    // P2: buf0 (M0,N1)
    LOAD_B(0, 1, bN1); STAGE_A(1, tA1, 1);
    BAR(); MFMA_Q(0, 1, bN1); BAR();
    // P3: buf0 (M1,N0)
    LOAD_A(0, 1); STAGE_B(0, tN0, 0);
    BAR(); MFMA_Q(1, 0, bN0); BAR();
    // P4: buf0 (M1,N1) + gate for buf1
    STAGE_B(0, tN0, 1);
    BAR(); MFMA_Q(1, 1, bN1); VMW(4); BAR();
    // P5: buf1 (M0,N0)
    LOAD_A(1, 0); LOAD_B(1, 0, bN0); STAGE_A(0, tN0, 0);
    BAR(); MFMA_Q(0, 0, bN0); BAR();
    // P6: buf1 (M0,N1)
    LOAD_B(1, 1, bN1); STAGE_A(0, tN0, 1);
    BAR(); MFMA_Q(0, 1, bN1); BAR();
    // P7: buf1 (M1,N0)
    LOAD_A(1, 1); STAGE_B(1, tN1, 0);
    BAR(); MFMA_Q(1, 0, bN0); BAR();
    // P8: buf1 (M1,N1) + gate for next buf0
    STAGE_B(1, tN1, 1);
    BAR(); MFMA_Q(1, 1, bN1); VMW(4); BAR();
  }

  // ---- epilogue. 32x32 C/D (m74/m101): col = lane&31,
  // row = (reg&3) + 8*(reg>>2) + 4*(lane>>5).
  VMW(0);
  float* base = C + (size_t)(bm0 + wm * 128) * NOUT + bn0 + wn * 64;
#pragma unroll
  for (int mf = 0; mf < 4; ++mf)
#pragma unroll
    for (int nf = 0; nf < 2; ++nf) {
      f32x16 v = acc[mf][nf];
#pragma unroll
      for (int r = 0; r < 16; ++r) {
        const int rowi = mf * 32 + (r & 3) + 8 * (r >> 2) + 4 * lh;
        base[(size_t)rowi * NOUT + nf * 32 + l31] = v[r];
      }
    }

#undef LOAD_A
#undef LOAD_B
#undef STAGE_A
#undef STAGE_B
#undef MFMA_Q
}

extern "C" void kernel_launch(void* const* d_in, const int* in_sizes, int n_in,
                              void* d_out, int out_size, void* d_ws, size_t ws_size,
                              hipStream_t stream) {
  const float* x   = (const float*)d_in[0];   // [4,2048,4096] f32
  const float* sv  = (const float*)d_in[1];   // [4096,1024] f32
  const void*  idx = d_in[2];                 // [1024] int32 or int64
  float* out = (float*)d_out;                 // [4,2048,4096] f32

  unsigned short* xg = (unsigned short*)d_ws;                 // [8192,1024] bf16
  unsigned short* wb = xg + (size_t)MROWS * KDIM;             // [4096,1024] bf16

  prep<<<2560, 512, 0, stream>>>(x, idx, sv, xg, wb);

  dim3 grid(NOUT / 256, MROWS / 256);  // (16, 32) = 512 blocks
  gemm256<<<grid, 512, 0, stream>>>(xg, wb, out);
}